// Round 2
// baseline (172.451 us; speedup 1.0000x reference)
//
#include <hip/hip_runtime.h>
#include <hip/hip_bf16.h>
#include <stdint.h>

// Problem constants (B,T,C,E) = (4,2048,1024,8)
#define NB 4
#define NT 2048
#define NC 1024
#define NE 8
#define NTOK (NB * NT)   // 8192 tokens

typedef __attribute__((ext_vector_type(4))) float floatx4;
typedef __attribute__((ext_vector_type(8))) __bf16 bf16x8;
typedef unsigned short ushort_t;

#define AS1 __attribute__((address_space(1)))
#define AS3 __attribute__((address_space(3)))

__device__ __forceinline__ ushort_t f2bf(float f) {
    uint32_t u = __builtin_bit_cast(uint32_t, f);
    u += 0x7FFFu + ((u >> 16) & 1u);   // round-to-nearest-even
    return (ushort_t)(u >> 16);
}

__device__ __forceinline__ void gload_lds16(const void* g, void* l) {
    __builtin_amdgcn_global_load_lds((const AS1 unsigned int*)g,
                                     (AS3 unsigned int*)l, 16, 0, 0);
}

__global__ void zero_counts_k(int* __restrict__ counts) {
    if (threadIdx.x < NE) counts[threadIdx.x] = 0;
}

// fp32 -> bf16 bulk convert (8 elems/thread)
__global__ __launch_bounds__(256) void convert_bf16_k(
    const float* __restrict__ src, ushort_t* __restrict__ dst)
{
    const size_t i = ((size_t)blockIdx.x * 256 + threadIdx.x) * 8;
    float4 a = *(const float4*)(src + i);
    float4 b = *(const float4*)(src + i + 4);
    union { bf16x8 v; ushort_t s[8]; } p;
    p.s[0] = f2bf(a.x); p.s[1] = f2bf(a.y); p.s[2] = f2bf(a.z); p.s[3] = f2bf(a.w);
    p.s[4] = f2bf(b.x); p.s[5] = f2bf(b.y); p.s[6] = f2bf(b.z); p.s[7] = f2bf(b.w);
    *(bf16x8*)(dst + i) = p.v;
}

// One wave per token: router logits -> softmax decision -> bucket (or zero
// output row). Also emits the bf16 copy of x (row already in registers).
__global__ __launch_bounds__(256) void router_k(
    const float* __restrict__ x, const float* __restrict__ Wr,
    const float* __restrict__ br, float* __restrict__ out,
    int* __restrict__ counts, int* __restrict__ buckets,
    ushort_t* __restrict__ xbf /* may be null (fallback path) */)
{
    const int wave = threadIdx.x >> 6;
    const int lane = threadIdx.x & 63;
    const int tok  = blockIdx.x * 4 + wave;

    const float4* xr = (const float4*)(x + (size_t)tok * NC);
    float4 xv[4];
#pragma unroll
    for (int j = 0; j < 4; ++j) xv[j] = xr[lane + 64 * j];

    if (xbf) {  // bf16 copy of x for the GEMM (uniform branch)
        typedef __attribute__((ext_vector_type(4))) __bf16 bf16x4;
        union { bf16x4 v; ushort_t s[4]; } p;
#pragma unroll
        for (int j = 0; j < 4; ++j) {
            p.s[0] = f2bf(xv[j].x); p.s[1] = f2bf(xv[j].y);
            p.s[2] = f2bf(xv[j].z); p.s[3] = f2bf(xv[j].w);
            *(bf16x4*)(xbf + (size_t)tok * NC + (lane + 64 * j) * 4) = p.v;
        }
    }

    float acc[NE];
#pragma unroll
    for (int e = 0; e < NE; ++e) {
        const float4* wr = (const float4*)(Wr + e * NC);
        float a = 0.f;
#pragma unroll
        for (int j = 0; j < 4; ++j) {
            float4 w = wr[lane + 64 * j];
            a += xv[j].x * w.x; a += xv[j].y * w.y;
            a += xv[j].z * w.z; a += xv[j].w * w.w;
        }
        acc[e] = a;
    }
#pragma unroll
    for (int off = 32; off >= 1; off >>= 1)
#pragma unroll
        for (int e = 0; e < NE; ++e) acc[e] += __shfl_xor(acc[e], off);

#pragma unroll
    for (int e = 0; e < NE; ++e) acc[e] += br[e];

    float lmax = acc[0]; int emax = 0;
#pragma unroll
    for (int e = 1; e < NE; ++e) if (acc[e] > lmax) { lmax = acc[e]; emax = e; }
    float S = 0.f;
#pragma unroll
    for (int e = 0; e < NE; ++e) S += expf(acc[e] - lmax);

    const bool routed = (S < 2.0f);   // gate_max = 1/S > 0.5
    if (routed) {
        if (lane == 0) {
            int pos = atomicAdd(&counts[emax], 1);
            buckets[emax * NTOK + pos] = tok;
        }
    } else {
        float4 z = make_float4(0.f, 0.f, 0.f, 0.f);
        float4* orow = (float4*)(out + (size_t)tok * NC);
#pragma unroll
        for (int j = 0; j < 4; ++j) orow[lane + 64 * j] = z;
    }
}

// ---------- fast path: bf16 grouped GEMM, m97 structure ----------
// 128x128 tile, BK=64, 4 waves (2x2), each wave 64x64 via 4x4 16x16x32 frags.
__global__ __launch_bounds__(256) void moe_gemm_bf16_k(
    const ushort_t* __restrict__ xbf, const ushort_t* __restrict__ webf,
    const float* __restrict__ be, float* __restrict__ out,
    const int* __restrict__ counts, const int* __restrict__ buckets)
{
    const int e   = blockIdx.z;
    const int cnt = counts[e];
    const int m0  = blockIdx.x * 128;
    if (m0 >= cnt) return;
    const int n0  = blockIdx.y * 128;

    __shared__ ushort_t As[128 * 64];   // 16 KB, linear (gload_lds dest)
    __shared__ ushort_t Bs[128 * 64];   // 16 KB

    const int tid   = threadIdx.x;
    const int wave  = tid >> 6, lane = tid & 63;
    const int chunk = tid & 7;          // 16B chunk within a 64-elem row
    const int rbase = tid >> 3;         // 0..31

    const ushort_t* asrc[4];
    const ushort_t* bsrc[4];
#pragma unroll
    for (int i = 0; i < 4; ++i) {
        const int arow = i * 32 + rbase;           // 0..127
        int mi = m0 + arow; if (mi >= cnt) mi = cnt - 1;
        const int tok = buckets[e * NTOK + mi];
        asrc[i] = xbf + (size_t)tok * NC + chunk * 8;
        bsrc[i] = webf + ((size_t)(e * 1024 + n0 + arow)) * NC + chunk * 8;
    }

    const int wm = (wave >> 1) * 64, wn = (wave & 1) * 64;
    const int fr = lane & 15, fk = (lane >> 4) * 8;

    floatx4 acc[4][4];
#pragma unroll
    for (int m = 0; m < 4; ++m)
#pragma unroll
        for (int n = 0; n < 4; ++n) acc[m][n] = (floatx4)(0.0f);

    for (int k0 = 0; k0 < NC; k0 += 64) {
#pragma unroll
        for (int i = 0; i < 4; ++i)
            gload_lds16(asrc[i] + k0, &As[((i * 256 + tid)) * 8]);
#pragma unroll
        for (int i = 0; i < 4; ++i)
            gload_lds16(bsrc[i] + k0, &Bs[((i * 256 + tid)) * 8]);
        __syncthreads();   // staging complete (vmcnt drained by barrier)
#pragma unroll
        for (int ks = 0; ks < 2; ++ks) {
            bf16x8 af[4], bfv[4];
#pragma unroll
            for (int m = 0; m < 4; ++m)
                af[m] = *(const bf16x8*)&As[(wm + m * 16 + fr) * 64 + ks * 32 + fk];
#pragma unroll
            for (int n = 0; n < 4; ++n)
                bfv[n] = *(const bf16x8*)&Bs[(wn + n * 16 + fr) * 64 + ks * 32 + fk];
#pragma unroll
            for (int m = 0; m < 4; ++m)
#pragma unroll
                for (int n = 0; n < 4; ++n)
                    acc[m][n] = __builtin_amdgcn_mfma_f32_16x16x32_bf16(
                        af[m], bfv[n], acc[m][n], 0, 0, 0);
        }
        __syncthreads();   // safe to overwrite LDS
    }

    // Epilogue: D layout col=lane&15, row=(lane>>4)*4+reg (m89-verified)
    const int r4 = (lane >> 4) * 4;
    float bev[4];
#pragma unroll
    for (int n = 0; n < 4; ++n) bev[n] = be[e * NC + n0 + wn + n * 16 + fr];
#pragma unroll
    for (int m = 0; m < 4; ++m) {
#pragma unroll
        for (int j = 0; j < 4; ++j) {
            const int trow = m0 + wm + m * 16 + r4 + j;
            if (trow < cnt) {
                const int tok = buckets[e * NTOK + trow];
                float* orow = out + (size_t)tok * NC + n0 + wn + fr;
#pragma unroll
                for (int n = 0; n < 4; ++n) orow[n * 16] = acc[m][n][j] + bev[n];
            }
        }
    }
}

// ---------- fallback path (round-1 kernel, fp32 staging) ----------
#define BM 64
#define BN 64
#define BK 32
#define LPAD 40
__global__ __launch_bounds__(256) void moe_gemm_k(
    const float* __restrict__ x, const float* __restrict__ We,
    const float* __restrict__ be, float* __restrict__ out,
    const int* __restrict__ counts, const int* __restrict__ buckets)
{
    const int e   = blockIdx.z;
    const int cnt = counts[e];
    const int m0  = blockIdx.x * BM;
    if (m0 >= cnt) return;
    const int n0  = blockIdx.y * BN;

    __shared__ ushort_t As[BM * LPAD];
    __shared__ ushort_t Bs[BM * LPAD];

    const int tid  = threadIdx.x;
    const int srow = tid >> 2;
    const int scg  = (tid & 3) * 8;

    const int mrow = m0 + srow;
    const int tokA = (mrow < cnt) ? buckets[e * NTOK + mrow] : -1;
    const float* xrow = x + (size_t)(tokA < 0 ? 0 : tokA) * NC;
    const float* wrow = We + ((size_t)e * NC + (n0 + srow)) * NC;

    const int wave = tid >> 6, lane = tid & 63;
    const int wm = (wave >> 1) * 32, wn = (wave & 1) * 32;
    const int fr = lane & 15;
    const int fk = (lane >> 4) * 8;

    floatx4 acc[2][2];
#pragma unroll
    for (int m = 0; m < 2; ++m)
#pragma unroll
        for (int n = 0; n < 2; ++n) acc[m][n] = (floatx4)(0.0f);

    for (int k0 = 0; k0 < NC; k0 += BK) {
        float4 a0 = make_float4(0.f,0.f,0.f,0.f), a1 = a0;
        if (tokA >= 0) {
            a0 = *(const float4*)(xrow + k0 + scg);
            a1 = *(const float4*)(xrow + k0 + scg + 4);
        }
        float4 b0 = *(const float4*)(wrow + k0 + scg);
        float4 b1 = *(const float4*)(wrow + k0 + scg + 4);

        __syncthreads();
        union { bf16x8 v; ushort_t s[8]; } pa, pb;
        pa.s[0] = f2bf(a0.x); pa.s[1] = f2bf(a0.y); pa.s[2] = f2bf(a0.z); pa.s[3] = f2bf(a0.w);
        pa.s[4] = f2bf(a1.x); pa.s[5] = f2bf(a1.y); pa.s[6] = f2bf(a1.z); pa.s[7] = f2bf(a1.w);
        pb.s[0] = f2bf(b0.x); pb.s[1] = f2bf(b0.y); pb.s[2] = f2bf(b0.z); pb.s[3] = f2bf(b0.w);
        pb.s[4] = f2bf(b1.x); pb.s[5] = f2bf(b1.y); pb.s[6] = f2bf(b1.z); pb.s[7] = f2bf(b1.w);
        *(bf16x8*)&As[srow * LPAD + scg] = pa.v;
        *(bf16x8*)&Bs[srow * LPAD + scg] = pb.v;
        __syncthreads();

        bf16x8 af[2], bfr[2];
#pragma unroll
        for (int m = 0; m < 2; ++m)
            af[m] = *(const bf16x8*)&As[(wm + m * 16 + fr) * LPAD + fk];
#pragma unroll
        for (int n = 0; n < 2; ++n)
            bfr[n] = *(const bf16x8*)&Bs[(wn + n * 16 + fr) * LPAD + fk];
#pragma unroll
        for (int m = 0; m < 2; ++m)
#pragma unroll
            for (int n = 0; n < 2; ++n)
                acc[m][n] = __builtin_amdgcn_mfma_f32_16x16x32_bf16(af[m], bfr[n], acc[m][n], 0, 0, 0);
    }

    const int r4 = (lane >> 4) * 4;
#pragma unroll
    for (int m = 0; m < 2; ++m) {
        const int trowb = m0 + wm + m * 16 + r4;
#pragma unroll
        for (int j = 0; j < 4; ++j) {
            const int trow = trowb + j;
            if (trow < cnt) {
                const int tok = buckets[e * NTOK + trow];
#pragma unroll
                for (int n = 0; n < 2; ++n) {
                    const int d = n0 + wn + n * 16 + fr;
                    out[(size_t)tok * NC + d] = acc[m][n][j] + be[e * NC + d];
                }
            }
        }
    }
}

extern "C" void kernel_launch(void* const* d_in, const int* in_sizes, int n_in,
                              void* d_out, int out_size, void* d_ws, size_t ws_size,
                              hipStream_t stream)
{
    const float* x  = (const float*)d_in[0];
    const float* Wr = (const float*)d_in[1];
    const float* br = (const float*)d_in[2];
    const float* We = (const float*)d_in[3];
    const float* be = (const float*)d_in[4];
    float* out = (float*)d_out;

    // ws layout (bytes):
    //   [0,256)                       counts (8 ints used)
    //   [256, 256+8*8192*4)           buckets            -> ends at 262400
    //   [262400, +16777216)           x bf16  (8192x1024)
    //   [17039616, +16777216)         We bf16 (8x1024x1024)
    int* counts  = (int*)d_ws;
    int* buckets = (int*)d_ws + 64;
    const size_t XBF_OFF = 262400;
    const size_t WBF_OFF = 17039616;
    const size_t WS_NEED = 33816832;
    const bool fast = (ws_size >= WS_NEED);

    ushort_t* xbf  = fast ? (ushort_t*)((char*)d_ws + XBF_OFF) : nullptr;
    ushort_t* webf = fast ? (ushort_t*)((char*)d_ws + WBF_OFF) : nullptr;

    hipLaunchKernelGGL(zero_counts_k, dim3(1), dim3(64), 0, stream, counts);
    hipLaunchKernelGGL(router_k, dim3(NTOK / 4), dim3(256), 0, stream,
                       x, Wr, br, out, counts, buckets, xbf);
    if (fast) {
        hipLaunchKernelGGL(convert_bf16_k, dim3((NE * NC * NC) / (256 * 8)), dim3(256),
                           0, stream, We, webf);
        hipLaunchKernelGGL(moe_gemm_bf16_k, dim3(NTOK / 128, NC / 128, NE), dim3(256),
                           0, stream, xbf, webf, be, out, counts, buckets);
    } else {
        hipLaunchKernelGGL(moe_gemm_k, dim3(NTOK / BM, NC / BN, NE), dim3(256),
                           0, stream, x, We, be, out, counts, buckets);
    }
}

// Round 3
// 93.231 us; speedup vs baseline: 1.8497x; 1.8497x over previous
//
#include <hip/hip_runtime.h>
#include <hip/hip_bf16.h>
#include <stdint.h>

// Problem constants (B,T,C,E) = (4,2048,1024,8)
#define NB 4
#define NT 2048
#define NC 1024
#define NE 8
#define NTOK (NB * NT)           // 8192 tokens
#define MAXT (NTOK / 128 + NE - 1)  // 71 worst-case M-tiles across experts

typedef __attribute__((ext_vector_type(4))) float floatx4;
typedef __attribute__((ext_vector_type(8))) __bf16 bf16x8;
typedef unsigned short ushort_t;

#define AS1 __attribute__((address_space(1)))
#define AS3 __attribute__((address_space(3)))

__device__ __forceinline__ ushort_t f2bf(float f) {
    uint32_t u = __builtin_bit_cast(uint32_t, f);
    u += 0x7FFFu + ((u >> 16) & 1u);   // round-to-nearest-even
    return (ushort_t)(u >> 16);
}

__device__ __forceinline__ void gload_lds16(const void* g, void* l) {
    __builtin_amdgcn_global_load_lds((const AS1 unsigned int*)g,
                                     (AS3 unsigned int*)l, 16, 0, 0);
}

__global__ void zero_counts_k(int* __restrict__ counts) {
    if (threadIdx.x < NE) counts[threadIdx.x] = 0;
}

// fp32 -> bf16 bulk convert (8 elems/thread)
__global__ __launch_bounds__(256) void convert_bf16_k(
    const float* __restrict__ src, ushort_t* __restrict__ dst)
{
    const size_t i = ((size_t)blockIdx.x * 256 + threadIdx.x) * 8;
    float4 a = *(const float4*)(src + i);
    float4 b = *(const float4*)(src + i + 4);
    union { bf16x8 v; ushort_t s[8]; } p;
    p.s[0] = f2bf(a.x); p.s[1] = f2bf(a.y); p.s[2] = f2bf(a.z); p.s[3] = f2bf(a.w);
    p.s[4] = f2bf(b.x); p.s[5] = f2bf(b.y); p.s[6] = f2bf(b.z); p.s[7] = f2bf(b.w);
    *(bf16x8*)(dst + i) = p.v;
}

// One wave per token: router logits -> softmax decision -> bucket (or zero
// output row). Also emits the bf16 copy of x (row already in registers).
__global__ __launch_bounds__(256) void router_k(
    const float* __restrict__ x, const float* __restrict__ Wr,
    const float* __restrict__ br, float* __restrict__ out,
    int* __restrict__ counts, int* __restrict__ buckets,
    ushort_t* __restrict__ xbf /* may be null (fallback path) */)
{
    const int wave = threadIdx.x >> 6;
    const int lane = threadIdx.x & 63;
    const int tok  = blockIdx.x * 4 + wave;

    const float4* xr = (const float4*)(x + (size_t)tok * NC);
    float4 xv[4];
#pragma unroll
    for (int j = 0; j < 4; ++j) xv[j] = xr[lane + 64 * j];

    if (xbf) {  // bf16 copy of x for the GEMM (uniform branch)
        typedef __attribute__((ext_vector_type(4))) __bf16 bf16x4;
        union { bf16x4 v; ushort_t s[4]; } p;
#pragma unroll
        for (int j = 0; j < 4; ++j) {
            p.s[0] = f2bf(xv[j].x); p.s[1] = f2bf(xv[j].y);
            p.s[2] = f2bf(xv[j].z); p.s[3] = f2bf(xv[j].w);
            *(bf16x4*)(xbf + (size_t)tok * NC + (lane + 64 * j) * 4) = p.v;
        }
    }

    float acc[NE];
#pragma unroll
    for (int e = 0; e < NE; ++e) {
        const float4* wr = (const float4*)(Wr + e * NC);
        float a = 0.f;
#pragma unroll
        for (int j = 0; j < 4; ++j) {
            float4 w = wr[lane + 64 * j];
            a += xv[j].x * w.x; a += xv[j].y * w.y;
            a += xv[j].z * w.z; a += xv[j].w * w.w;
        }
        acc[e] = a;
    }
#pragma unroll
    for (int off = 32; off >= 1; off >>= 1)
#pragma unroll
        for (int e = 0; e < NE; ++e) acc[e] += __shfl_xor(acc[e], off);

#pragma unroll
    for (int e = 0; e < NE; ++e) acc[e] += br[e];

    float lmax = acc[0]; int emax = 0;
#pragma unroll
    for (int e = 1; e < NE; ++e) if (acc[e] > lmax) { lmax = acc[e]; emax = e; }
    float S = 0.f;
#pragma unroll
    for (int e = 0; e < NE; ++e) S += expf(acc[e] - lmax);

    const bool routed = (S < 2.0f);   // gate_max = 1/S > 0.5
    if (routed) {
        if (lane == 0) {
            int pos = atomicAdd(&counts[emax], 1);
            buckets[emax * NTOK + pos] = tok;
        }
    } else {
        float4 z = make_float4(0.f, 0.f, 0.f, 0.f);
        float4* orow = (float4*)(out + (size_t)tok * NC);
#pragma unroll
        for (int j = 0; j < 4; ++j) orow[lane + 64 * j] = z;
    }
}

// ---------- fast path: bf16 grouped GEMM, m97 structure + compacted grid ----------
// Fixed grid (MAXT, 8): block maps linear tile id -> (expert, m-tile) via an
// in-register prefix sum over counts. 128x128 tile, BK=64, 4 waves (2x2),
// each wave 64x64 via 4x4 16x16x32 frags. LDS linear (gload_lds dest);
// bank-conflict fix = XOR-swizzle the 16B chunk on BOTH the global source
// address and the frag-read address (same involution, rule #21).
__global__ __launch_bounds__(256) void moe_gemm_bf16_k(
    const ushort_t* __restrict__ xbf, const ushort_t* __restrict__ webf,
    const float* __restrict__ be, float* __restrict__ out,
    const int* __restrict__ counts, const int* __restrict__ buckets)
{
    int cw[NE];
#pragma unroll
    for (int i = 0; i < NE; ++i) cw[i] = counts[i];
    const int t = blockIdx.x;
    int base = 0, e = -1, m0 = 0;
#pragma unroll
    for (int i = 0; i < NE; ++i) {
        const int te = (cw[i] + 127) >> 7;
        if (e < 0 && t < base + te) { e = i; m0 = (t - base) << 7; }
        base += te;
    }
    if (e < 0) return;
    const int cnt = cw[e];
    const int n0  = blockIdx.y * 128;

    __shared__ ushort_t As[128 * 64];   // 16 KB, linear (gload_lds dest)
    __shared__ ushort_t Bs[128 * 64];   // 16 KB

    const int tid   = threadIdx.x;
    const int wave  = tid >> 6, lane = tid & 63;
    const int chunk = tid & 7;          // 16B chunk within a 64-elem K-slice
    const int rbase = tid >> 3;         // 0..31

    const ushort_t* asrc[4];
    const ushort_t* bsrc[4];
#pragma unroll
    for (int i = 0; i < 4; ++i) {
        const int row = i * 32 + rbase;            // 0..127
        const int sc  = chunk ^ (row & 7);         // pre-swizzled source chunk
        int mi = m0 + row; if (mi >= cnt) mi = cnt - 1;
        const int tok = buckets[e * NTOK + mi];
        asrc[i] = xbf + (size_t)tok * NC + sc * 8;
        bsrc[i] = webf + ((size_t)(e * 1024 + n0 + row)) * NC + sc * 8;
    }

    const int wm = (wave >> 1) * 64, wn = (wave & 1) * 64;
    const int fr = lane & 15, hi = lane >> 4;

    floatx4 acc[4][4];
#pragma unroll
    for (int m = 0; m < 4; ++m)
#pragma unroll
        for (int n = 0; n < 4; ++n) acc[m][n] = (floatx4)(0.0f);

    for (int k0 = 0; k0 < NC; k0 += 64) {
#pragma unroll
        for (int i = 0; i < 4; ++i)
            gload_lds16(asrc[i] + k0, &As[(i * 256 + tid) * 8]);
#pragma unroll
        for (int i = 0; i < 4; ++i)
            gload_lds16(bsrc[i] + k0, &Bs[(i * 256 + tid) * 8]);
        __syncthreads();   // staging complete
#pragma unroll
        for (int ks = 0; ks < 2; ++ks) {
            bf16x8 af[4], bfv[4];
#pragma unroll
            for (int m = 0; m < 4; ++m) {
                const int row = wm + m * 16 + fr;
                const int cg  = (ks * 4 + hi) ^ (row & 7);   // swizzled read chunk
                af[m] = *(const bf16x8*)((const char*)As + row * 128 + cg * 16);
            }
#pragma unroll
            for (int n = 0; n < 4; ++n) {
                const int row = wn + n * 16 + fr;
                const int cg  = (ks * 4 + hi) ^ (row & 7);
                bfv[n] = *(const bf16x8*)((const char*)Bs + row * 128 + cg * 16);
            }
#pragma unroll
            for (int m = 0; m < 4; ++m)
#pragma unroll
                for (int n = 0; n < 4; ++n)
                    acc[m][n] = __builtin_amdgcn_mfma_f32_16x16x32_bf16(
                        af[m], bfv[n], acc[m][n], 0, 0, 0);
        }
        __syncthreads();   // safe to overwrite LDS
    }

    // Epilogue: D layout col=lane&15, row=(lane>>4)*4+reg (m89-verified)
    const int r4 = (lane >> 4) * 4;
    float bev[4];
#pragma unroll
    for (int n = 0; n < 4; ++n) bev[n] = be[e * NC + n0 + wn + n * 16 + fr];
#pragma unroll
    for (int m = 0; m < 4; ++m) {
#pragma unroll
        for (int j = 0; j < 4; ++j) {
            const int trow = m0 + wm + m * 16 + r4 + j;
            if (trow < cnt) {
                const int tok = buckets[e * NTOK + trow];
                float* orow = out + (size_t)tok * NC + n0 + wn + fr;
#pragma unroll
                for (int n = 0; n < 4; ++n) orow[n * 16] = acc[m][n][j] + bev[n];
            }
        }
    }
}

// ---------- fallback path (round-1 kernel, fp32 staging) ----------
#define BM 64
#define BN 64
#define BK 32
#define LPAD 40
__global__ __launch_bounds__(256) void moe_gemm_k(
    const float* __restrict__ x, const float* __restrict__ We,
    const float* __restrict__ be, float* __restrict__ out,
    const int* __restrict__ counts, const int* __restrict__ buckets)
{
    const int e   = blockIdx.z;
    const int cnt = counts[e];
    const int m0  = blockIdx.x * BM;
    if (m0 >= cnt) return;
    const int n0  = blockIdx.y * BN;

    __shared__ ushort_t As[BM * LPAD];
    __shared__ ushort_t Bs[BM * LPAD];

    const int tid  = threadIdx.x;
    const int srow = tid >> 2;
    const int scg  = (tid & 3) * 8;

    const int mrow = m0 + srow;
    const int tokA = (mrow < cnt) ? buckets[e * NTOK + mrow] : -1;
    const float* xrow = x + (size_t)(tokA < 0 ? 0 : tokA) * NC;
    const float* wrow = We + ((size_t)e * NC + (n0 + srow)) * NC;

    const int wave = tid >> 6, lane = tid & 63;
    const int wm = (wave >> 1) * 32, wn = (wave & 1) * 32;
    const int fr = lane & 15;
    const int fk = (lane >> 4) * 8;

    floatx4 acc[2][2];
#pragma unroll
    for (int m = 0; m < 2; ++m)
#pragma unroll
        for (int n = 0; n < 2; ++n) acc[m][n] = (floatx4)(0.0f);

    for (int k0 = 0; k0 < NC; k0 += BK) {
        float4 a0 = make_float4(0.f,0.f,0.f,0.f), a1 = a0;
        if (tokA >= 0) {
            a0 = *(const float4*)(xrow + k0 + scg);
            a1 = *(const float4*)(xrow + k0 + scg + 4);
        }
        float4 b0 = *(const float4*)(wrow + k0 + scg);
        float4 b1 = *(const float4*)(wrow + k0 + scg + 4);

        __syncthreads();
        union { bf16x8 v; ushort_t s[8]; } pa, pb;
        pa.s[0] = f2bf(a0.x); pa.s[1] = f2bf(a0.y); pa.s[2] = f2bf(a0.z); pa.s[3] = f2bf(a0.w);
        pa.s[4] = f2bf(a1.x); pa.s[5] = f2bf(a1.y); pa.s[6] = f2bf(a1.z); pa.s[7] = f2bf(a1.w);
        pb.s[0] = f2bf(b0.x); pb.s[1] = f2bf(b0.y); pb.s[2] = f2bf(b0.z); pb.s[3] = f2bf(b0.w);
        pb.s[4] = f2bf(b1.x); pb.s[5] = f2bf(b1.y); pb.s[6] = f2bf(b1.z); pb.s[7] = f2bf(b1.w);
        *(bf16x8*)&As[srow * LPAD + scg] = pa.v;
        *(bf16x8*)&Bs[srow * LPAD + scg] = pb.v;
        __syncthreads();

        bf16x8 af[2], bfr[2];
#pragma unroll
        for (int m = 0; m < 2; ++m)
            af[m] = *(const bf16x8*)&As[(wm + m * 16 + fr) * LPAD + fk];
#pragma unroll
        for (int n = 0; n < 2; ++n)
            bfr[n] = *(const bf16x8*)&Bs[(wn + n * 16 + fr) * LPAD + fk];
#pragma unroll
        for (int m = 0; m < 2; ++m)
#pragma unroll
            for (int n = 0; n < 2; ++n)
                acc[m][n] = __builtin_amdgcn_mfma_f32_16x16x32_bf16(af[m], bfr[n], acc[m][n], 0, 0, 0);
    }

    const int r4 = (lane >> 4) * 4;
#pragma unroll
    for (int m = 0; m < 2; ++m) {
        const int trowb = m0 + wm + m * 16 + r4;
#pragma unroll
        for (int j = 0; j < 4; ++j) {
            const int trow = trowb + j;
            if (trow < cnt) {
                const int tok = buckets[e * NTOK + trow];
#pragma unroll
                for (int n = 0; n < 2; ++n) {
                    const int d = n0 + wn + n * 16 + fr;
                    out[(size_t)tok * NC + d] = acc[m][n][j] + be[e * NC + d];
                }
            }
        }
    }
}

extern "C" void kernel_launch(void* const* d_in, const int* in_sizes, int n_in,
                              void* d_out, int out_size, void* d_ws, size_t ws_size,
                              hipStream_t stream)
{
    const float* x  = (const float*)d_in[0];
    const float* Wr = (const float*)d_in[1];
    const float* br = (const float*)d_in[2];
    const float* We = (const float*)d_in[3];
    const float* be = (const float*)d_in[4];
    float* out = (float*)d_out;

    int* counts  = (int*)d_ws;
    int* buckets = (int*)d_ws + 64;
    const size_t XBF_OFF = 262400;
    const size_t WBF_OFF = 17039616;
    const size_t WS_NEED = 33816832;
    const bool fast = (ws_size >= WS_NEED);

    ushort_t* xbf  = fast ? (ushort_t*)((char*)d_ws + XBF_OFF) : nullptr;
    ushort_t* webf = fast ? (ushort_t*)((char*)d_ws + WBF_OFF) : nullptr;

    hipLaunchKernelGGL(zero_counts_k, dim3(1), dim3(64), 0, stream, counts);
    hipLaunchKernelGGL(router_k, dim3(NTOK / 4), dim3(256), 0, stream,
                       x, Wr, br, out, counts, buckets, xbf);
    if (fast) {
        hipLaunchKernelGGL(convert_bf16_k, dim3((NE * NC * NC) / (256 * 8)), dim3(256),
                           0, stream, We, webf);
        hipLaunchKernelGGL(moe_gemm_bf16_k, dim3(MAXT, NC / 128, 1), dim3(256),
                           0, stream, xbf, webf, be, out, counts, buckets);
    } else {
        hipLaunchKernelGGL(moe_gemm_k, dim3(NTOK / BM, NC / BN, NE), dim3(256),
                           0, stream, x, We, be, out, counts, buckets);
    }
}

// Round 4
// 66.282 us; speedup vs baseline: 2.6018x; 1.4066x over previous
//
#include <hip/hip_runtime.h>
#include <hip/hip_bf16.h>
#include <stdint.h>

// Problem constants (B,T,C,E) = (4,2048,1024,8)
#define NB 4
#define NT 2048
#define NC 1024
#define NE 8
#define NTOK (NB * NT)              // 8192 tokens
#define MAXT (NTOK / 128 + NE - 1)  // 71 worst-case M-tiles across experts
#define CSTRIDE 32                  // counter padding: 32 ints = 128 B / expert

typedef __attribute__((ext_vector_type(4))) float floatx4;
typedef __attribute__((ext_vector_type(8))) __bf16 bf16x8;
typedef unsigned short ushort_t;

#define AS1 __attribute__((address_space(1)))
#define AS3 __attribute__((address_space(3)))

__device__ __forceinline__ ushort_t f2bf(float f) {
    uint32_t u = __builtin_bit_cast(uint32_t, f);
    u += 0x7FFFu + ((u >> 16) & 1u);   // round-to-nearest-even
    return (ushort_t)(u >> 16);
}

__global__ void zero_counts_k(int* __restrict__ counts) {
    if (threadIdx.x < NE) counts[threadIdx.x * CSTRIDE] = 0;
}

// One wave per token: router logits -> softmax decision -> bucket (padded
// counters) or zero output row. Routed tokens also emit their bf16 x row.
// The We->bf16 convert is FUSED in (grid-stride, loads issued early) so its
// independent memory traffic hides the routing/atomic latency.
__global__ __launch_bounds__(256, 6) void router_k(
    const float* __restrict__ x, const float* __restrict__ Wr,
    const float* __restrict__ br, float* __restrict__ out,
    int* __restrict__ counts, int* __restrict__ buckets,
    ushort_t* __restrict__ xbf /* null on fallback */,
    const float* __restrict__ We, ushort_t* __restrict__ webf /* null on fallback */)
{
    const int wave = threadIdx.x >> 6;
    const int lane = threadIdx.x & 63;
    const int tok  = blockIdx.x * 4 + wave;

    // --- fused convert: issue loads EARLY (independent MLP for every wave) ---
    const size_t cbase = ((size_t)(blockIdx.x * 256 + threadIdx.x)) * 8;
    float4 cva0, cvb0, cva1, cvb1;
    if (webf) {
        cva0 = *(const float4*)(We + cbase);
        cvb0 = *(const float4*)(We + cbase + 4);
        cva1 = *(const float4*)(We + cbase + 4194304);
        cvb1 = *(const float4*)(We + cbase + 4194304 + 4);
    }

    const float4* xr = (const float4*)(x + (size_t)tok * NC);
    float4 xv[4];
#pragma unroll
    for (int j = 0; j < 4; ++j) xv[j] = xr[lane + 64 * j];

    float acc[NE];
#pragma unroll
    for (int e = 0; e < NE; ++e) {
        const float4* wr = (const float4*)(Wr + e * NC);
        float a = 0.f;
#pragma unroll
        for (int j = 0; j < 4; ++j) {
            float4 w = wr[lane + 64 * j];
            a += xv[j].x * w.x; a += xv[j].y * w.y;
            a += xv[j].z * w.z; a += xv[j].w * w.w;
        }
        acc[e] = a;
    }
#pragma unroll
    for (int off = 32; off >= 1; off >>= 1)
#pragma unroll
        for (int e = 0; e < NE; ++e) acc[e] += __shfl_xor(acc[e], off);

#pragma unroll
    for (int e = 0; e < NE; ++e) acc[e] += br[e];

    float lmax = acc[0]; int emax = 0;
#pragma unroll
    for (int e = 1; e < NE; ++e) if (acc[e] > lmax) { lmax = acc[e]; emax = e; }
    float S = 0.f;
#pragma unroll
    for (int e = 0; e < NE; ++e) S += expf(acc[e] - lmax);

    const bool routed = (S < 2.0f);   // gate_max = 1/S > 0.5
    if (routed) {
        if (xbf) {  // bf16 x row needed only for routed tokens
            typedef __attribute__((ext_vector_type(4))) __bf16 bf16x4;
            union { bf16x4 v; ushort_t s[4]; } p;
#pragma unroll
            for (int j = 0; j < 4; ++j) {
                p.s[0] = f2bf(xv[j].x); p.s[1] = f2bf(xv[j].y);
                p.s[2] = f2bf(xv[j].z); p.s[3] = f2bf(xv[j].w);
                *(bf16x4*)(xbf + (size_t)tok * NC + (lane + 64 * j) * 4) = p.v;
            }
        }
        if (lane == 0) {
            int pos = atomicAdd(&counts[emax * CSTRIDE], 1);
            buckets[emax * NTOK + pos] = tok;
        }
    } else {
        float4 z = make_float4(0.f, 0.f, 0.f, 0.f);
        float4* orow = (float4*)(out + (size_t)tok * NC);
#pragma unroll
        for (int j = 0; j < 4; ++j) orow[lane + 64 * j] = z;
    }

    // --- fused convert: pack + store ---
    if (webf) {
        union { bf16x8 v; ushort_t s[8]; } p;
        p.s[0] = f2bf(cva0.x); p.s[1] = f2bf(cva0.y); p.s[2] = f2bf(cva0.z); p.s[3] = f2bf(cva0.w);
        p.s[4] = f2bf(cvb0.x); p.s[5] = f2bf(cvb0.y); p.s[6] = f2bf(cvb0.z); p.s[7] = f2bf(cvb0.w);
        *(bf16x8*)(webf + cbase) = p.v;
        p.s[0] = f2bf(cva1.x); p.s[1] = f2bf(cva1.y); p.s[2] = f2bf(cva1.z); p.s[3] = f2bf(cva1.w);
        p.s[4] = f2bf(cvb1.x); p.s[5] = f2bf(cvb1.y); p.s[6] = f2bf(cvb1.z); p.s[7] = f2bf(cvb1.w);
        *(bf16x8*)(webf + cbase + 4194304) = p.v;
    }
}

__device__ __forceinline__ void gload_lds16(const void* g, void* l) {
    __builtin_amdgcn_global_load_lds((const AS1 unsigned int*)g,
                                     (AS3 unsigned int*)l, 16, 0, 0);
}

// ---------- fast path: bf16 grouped GEMM, compacted grid + XOR swizzle ----------
__global__ __launch_bounds__(256) void moe_gemm_bf16_k(
    const ushort_t* __restrict__ xbf, const ushort_t* __restrict__ webf,
    const float* __restrict__ be, float* __restrict__ out,
    const int* __restrict__ counts, const int* __restrict__ buckets)
{
    int cw[NE];
#pragma unroll
    for (int i = 0; i < NE; ++i) cw[i] = counts[i * CSTRIDE];
    const int t = blockIdx.x;
    int base = 0, e = -1, m0 = 0;
#pragma unroll
    for (int i = 0; i < NE; ++i) {
        const int te = (cw[i] + 127) >> 7;
        if (e < 0 && t < base + te) { e = i; m0 = (t - base) << 7; }
        base += te;
    }
    if (e < 0) return;
    const int cnt = cw[e];
    const int n0  = blockIdx.y * 128;

    __shared__ ushort_t As[128 * 64];   // 16 KB, linear (gload_lds dest)
    __shared__ ushort_t Bs[128 * 64];   // 16 KB

    const int tid   = threadIdx.x;
    const int wave  = tid >> 6, lane = tid & 63;
    const int chunk = tid & 7;          // 16B chunk within a 64-elem K-slice
    const int rbase = tid >> 3;         // 0..31

    const ushort_t* asrc[4];
    const ushort_t* bsrc[4];
#pragma unroll
    for (int i = 0; i < 4; ++i) {
        const int row = i * 32 + rbase;            // 0..127
        const int sc  = chunk ^ (row & 7);         // pre-swizzled source chunk
        int mi = m0 + row; if (mi >= cnt) mi = cnt - 1;
        const int tok = buckets[e * NTOK + mi];
        asrc[i] = xbf + (size_t)tok * NC + sc * 8;
        bsrc[i] = webf + ((size_t)(e * 1024 + n0 + row)) * NC + sc * 8;
    }

    const int wm = (wave >> 1) * 64, wn = (wave & 1) * 64;
    const int fr = lane & 15, hi = lane >> 4;

    floatx4 acc[4][4];
#pragma unroll
    for (int m = 0; m < 4; ++m)
#pragma unroll
        for (int n = 0; n < 4; ++n) acc[m][n] = (floatx4)(0.0f);

    for (int k0 = 0; k0 < NC; k0 += 64) {
#pragma unroll
        for (int i = 0; i < 4; ++i)
            gload_lds16(asrc[i] + k0, &As[(i * 256 + tid) * 8]);
#pragma unroll
        for (int i = 0; i < 4; ++i)
            gload_lds16(bsrc[i] + k0, &Bs[(i * 256 + tid) * 8]);
        __syncthreads();   // staging complete
#pragma unroll
        for (int ks = 0; ks < 2; ++ks) {
            bf16x8 af[4], bfv[4];
#pragma unroll
            for (int m = 0; m < 4; ++m) {
                const int row = wm + m * 16 + fr;
                const int cg  = (ks * 4 + hi) ^ (row & 7);   // swizzled read chunk
                af[m] = *(const bf16x8*)((const char*)As + row * 128 + cg * 16);
            }
#pragma unroll
            for (int n = 0; n < 4; ++n) {
                const int row = wn + n * 16 + fr;
                const int cg  = (ks * 4 + hi) ^ (row & 7);
                bfv[n] = *(const bf16x8*)((const char*)Bs + row * 128 + cg * 16);
            }
#pragma unroll
            for (int m = 0; m < 4; ++m)
#pragma unroll
                for (int n = 0; n < 4; ++n)
                    acc[m][n] = __builtin_amdgcn_mfma_f32_16x16x32_bf16(
                        af[m], bfv[n], acc[m][n], 0, 0, 0);
        }
        __syncthreads();   // safe to overwrite LDS
    }

    // Epilogue: D layout col=lane&15, row=(lane>>4)*4+reg (m89-verified)
    const int r4 = (lane >> 4) * 4;
    float bev[4];
#pragma unroll
    for (int n = 0; n < 4; ++n) bev[n] = be[e * NC + n0 + wn + n * 16 + fr];
#pragma unroll
    for (int m = 0; m < 4; ++m) {
#pragma unroll
        for (int j = 0; j < 4; ++j) {
            const int trow = m0 + wm + m * 16 + r4 + j;
            if (trow < cnt) {
                const int tok = buckets[e * NTOK + trow];
                float* orow = out + (size_t)tok * NC + n0 + wn + fr;
#pragma unroll
                for (int n = 0; n < 4; ++n) orow[n * 16] = acc[m][n][j] + bev[n];
            }
        }
    }
}

// ---------- fallback path (fp32 staging, small ws) ----------
#define BM 64
#define BN 64
#define BK 32
#define LPAD 40
__global__ __launch_bounds__(256) void moe_gemm_k(
    const float* __restrict__ x, const float* __restrict__ We,
    const float* __restrict__ be, float* __restrict__ out,
    const int* __restrict__ counts, const int* __restrict__ buckets)
{
    const int e   = blockIdx.z;
    const int cnt = counts[e * CSTRIDE];
    const int m0  = blockIdx.x * BM;
    if (m0 >= cnt) return;
    const int n0  = blockIdx.y * BN;

    __shared__ ushort_t As[BM * LPAD];
    __shared__ ushort_t Bs[BM * LPAD];

    const int tid  = threadIdx.x;
    const int srow = tid >> 2;
    const int scg  = (tid & 3) * 8;

    const int mrow = m0 + srow;
    const int tokA = (mrow < cnt) ? buckets[e * NTOK + mrow] : -1;
    const float* xrow = x + (size_t)(tokA < 0 ? 0 : tokA) * NC;
    const float* wrow = We + ((size_t)e * NC + (n0 + srow)) * NC;

    const int wave = tid >> 6, lane = tid & 63;
    const int wm = (wave >> 1) * 32, wn = (wave & 1) * 32;
    const int fr = lane & 15;
    const int fk = (lane >> 4) * 8;

    floatx4 acc[2][2];
#pragma unroll
    for (int m = 0; m < 2; ++m)
#pragma unroll
        for (int n = 0; n < 2; ++n) acc[m][n] = (floatx4)(0.0f);

    for (int k0 = 0; k0 < NC; k0 += BK) {
        float4 a0 = make_float4(0.f,0.f,0.f,0.f), a1 = a0;
        if (tokA >= 0) {
            a0 = *(const float4*)(xrow + k0 + scg);
            a1 = *(const float4*)(xrow + k0 + scg + 4);
        }
        float4 b0 = *(const float4*)(wrow + k0 + scg);
        float4 b1 = *(const float4*)(wrow + k0 + scg + 4);

        __syncthreads();
        union { bf16x8 v; ushort_t s[8]; } pa, pb;
        pa.s[0] = f2bf(a0.x); pa.s[1] = f2bf(a0.y); pa.s[2] = f2bf(a0.z); pa.s[3] = f2bf(a0.w);
        pa.s[4] = f2bf(a1.x); pa.s[5] = f2bf(a1.y); pa.s[6] = f2bf(a1.z); pa.s[7] = f2bf(a1.w);
        pb.s[0] = f2bf(b0.x); pb.s[1] = f2bf(b0.y); pb.s[2] = f2bf(b0.z); pb.s[3] = f2bf(b0.w);
        pb.s[4] = f2bf(b1.x); pb.s[5] = f2bf(b1.y); pb.s[6] = f2bf(b1.z); pb.s[7] = f2bf(b1.w);
        *(bf16x8*)&As[srow * LPAD + scg] = pa.v;
        *(bf16x8*)&Bs[srow * LPAD + scg] = pb.v;
        __syncthreads();

        bf16x8 af[2], bfr[2];
#pragma unroll
        for (int m = 0; m < 2; ++m)
            af[m] = *(const bf16x8*)&As[(wm + m * 16 + fr) * LPAD + fk];
#pragma unroll
        for (int n = 0; n < 2; ++n)
            bfr[n] = *(const bf16x8*)&Bs[(wn + n * 16 + fr) * LPAD + fk];
#pragma unroll
        for (int m = 0; m < 2; ++m)
#pragma unroll
            for (int n = 0; n < 2; ++n)
                acc[m][n] = __builtin_amdgcn_mfma_f32_16x16x32_bf16(af[m], bfr[n], acc[m][n], 0, 0, 0);
    }

    const int r4 = (lane >> 4) * 4;
#pragma unroll
    for (int m = 0; m < 2; ++m) {
        const int trowb = m0 + wm + m * 16 + r4;
#pragma unroll
        for (int j = 0; j < 4; ++j) {
            const int trow = trowb + j;
            if (trow < cnt) {
                const int tok = buckets[e * NTOK + trow];
#pragma unroll
                for (int n = 0; n < 2; ++n) {
                    const int d = n0 + wn + n * 16 + fr;
                    out[(size_t)tok * NC + d] = acc[m][n][j] + be[e * NC + d];
                }
            }
        }
    }
}

extern "C" void kernel_launch(void* const* d_in, const int* in_sizes, int n_in,
                              void* d_out, int out_size, void* d_ws, size_t ws_size,
                              hipStream_t stream)
{
    const float* x  = (const float*)d_in[0];
    const float* Wr = (const float*)d_in[1];
    const float* br = (const float*)d_in[2];
    const float* We = (const float*)d_in[3];
    const float* be = (const float*)d_in[4];
    float* out = (float*)d_out;

    // ws layout (bytes):
    //   [0, 1024)              padded counts (8 x 128B)
    //   [1024, 1024+262144)    buckets (8 x 8192 ints)      -> ends 263168
    //   [263168, +16777216)    x bf16                        -> ends 17040384
    //   [17040384, +16777216)  We bf16                       -> ends 33817600
    int* counts  = (int*)d_ws;
    int* buckets = (int*)((char*)d_ws + 1024);
    const size_t XBF_OFF = 263168;
    const size_t WBF_OFF = 17040384;
    const size_t WS_NEED = 33817600;
    const bool fast = (ws_size >= WS_NEED);

    ushort_t* xbf  = fast ? (ushort_t*)((char*)d_ws + XBF_OFF) : nullptr;
    ushort_t* webf = fast ? (ushort_t*)((char*)d_ws + WBF_OFF) : nullptr;

    hipLaunchKernelGGL(zero_counts_k, dim3(1), dim3(64), 0, stream, counts);
    hipLaunchKernelGGL(router_k, dim3(NTOK / 4), dim3(256), 0, stream,
                       x, Wr, br, out, counts, buckets, xbf, We, webf);
    if (fast) {
        hipLaunchKernelGGL(moe_gemm_bf16_k, dim3(MAXT, NC / 128, 1), dim3(256),
                           0, stream, xbf, webf, be, out, counts, buckets);
    } else {
        hipLaunchKernelGGL(moe_gemm_k, dim3(NTOK / BM, NC / BN, NE), dim3(256),
                           0, stream, x, We, be, out, counts, buckets);
    }
}

// Round 5
// 66.092 us; speedup vs baseline: 2.6093x; 1.0029x over previous
//
#include <hip/hip_runtime.h>
#include <hip/hip_bf16.h>
#include <stdint.h>

// Problem constants (B,T,C,E) = (4,2048,1024,8)
#define NB 4
#define NT 2048
#define NC 1024
#define NE 8
#define NTOK (NB * NT)              // 8192 tokens
#define MAXT (NTOK / 128 + NE - 1)  // 71 worst-case M-tiles across experts
#define CSTRIDE 32                  // counter padding: 32 ints = 128 B / expert

typedef __attribute__((ext_vector_type(4))) float floatx4;
typedef __attribute__((ext_vector_type(8))) __bf16 bf16x8;
typedef __attribute__((ext_vector_type(4))) __bf16 bf16x4;
typedef unsigned short ushort_t;

#define AS1 __attribute__((address_space(1)))
#define AS3 __attribute__((address_space(3)))

__device__ __forceinline__ ushort_t f2bf(float f) {
    uint32_t u = __builtin_bit_cast(uint32_t, f);
    u += 0x7FFFu + ((u >> 16) & 1u);   // round-to-nearest-even
    return (ushort_t)(u >> 16);
}

// One wave per token. Structure is stream-through: (A) We->bf16 convert slice
// with immediate stores (<=16 live regs, retires), (B) x row load + immediate
// unconditional bf16 store, (C) fp32 routing math + bucket atomic (padded
// counters). No zero-writes: d_out is memset on the stream before this.
__global__ __launch_bounds__(256, 8) void router_k(
    const float* __restrict__ x, const float* __restrict__ Wr,
    const float* __restrict__ br,
    int* __restrict__ counts, int* __restrict__ buckets,
    ushort_t* __restrict__ xbf /* null on fallback */,
    const float* __restrict__ We, ushort_t* __restrict__ webf /* null on fallback */)
{
    const int wave = threadIdx.x >> 6;
    const int lane = threadIdx.x & 63;
    const int tok  = blockIdx.x * 4 + wave;

    // --- Phase A: fused We convert, stream-through (2 x 32B/thread) ---
    if (webf) {
        const size_t cbase = ((size_t)(blockIdx.x * 256 + threadIdx.x)) * 8;
        {
            float4 a = *(const float4*)(We + cbase);
            float4 b = *(const float4*)(We + cbase + 4);
            union { bf16x8 v; ushort_t s[8]; } p;
            p.s[0] = f2bf(a.x); p.s[1] = f2bf(a.y); p.s[2] = f2bf(a.z); p.s[3] = f2bf(a.w);
            p.s[4] = f2bf(b.x); p.s[5] = f2bf(b.y); p.s[6] = f2bf(b.z); p.s[7] = f2bf(b.w);
            *(bf16x8*)(webf + cbase) = p.v;
        }
        {
            float4 a = *(const float4*)(We + cbase + 4194304);
            float4 b = *(const float4*)(We + cbase + 4194304 + 4);
            union { bf16x8 v; ushort_t s[8]; } p;
            p.s[0] = f2bf(a.x); p.s[1] = f2bf(a.y); p.s[2] = f2bf(a.z); p.s[3] = f2bf(a.w);
            p.s[4] = f2bf(b.x); p.s[5] = f2bf(b.y); p.s[6] = f2bf(b.z); p.s[7] = f2bf(b.w);
            *(bf16x8*)(webf + cbase + 4194304) = p.v;
        }
    }

    // --- Phase B: x row load + immediate unconditional bf16 store ---
    const float4* xr = (const float4*)(x + (size_t)tok * NC);
    float4 xv[4];
#pragma unroll
    for (int j = 0; j < 4; ++j) xv[j] = xr[lane + 64 * j];

    if (xbf) {
        union { bf16x4 v; ushort_t s[4]; } p;
#pragma unroll
        for (int j = 0; j < 4; ++j) {
            p.s[0] = f2bf(xv[j].x); p.s[1] = f2bf(xv[j].y);
            p.s[2] = f2bf(xv[j].z); p.s[3] = f2bf(xv[j].w);
            *(bf16x4*)(xbf + (size_t)tok * NC + (lane + 64 * j) * 4) = p.v;
        }
    }

    // --- Phase C: fp32 routing (must match reference decisions exactly-ish) ---
    float acc[NE];
#pragma unroll
    for (int e = 0; e < NE; ++e) {
        const float4* wr = (const float4*)(Wr + e * NC);
        float a = 0.f;
#pragma unroll
        for (int j = 0; j < 4; ++j) {
            float4 w = wr[lane + 64 * j];
            a += xv[j].x * w.x; a += xv[j].y * w.y;
            a += xv[j].z * w.z; a += xv[j].w * w.w;
        }
        acc[e] = a;
    }
#pragma unroll
    for (int off = 32; off >= 1; off >>= 1)
#pragma unroll
        for (int e = 0; e < NE; ++e) acc[e] += __shfl_xor(acc[e], off);

#pragma unroll
    for (int e = 0; e < NE; ++e) acc[e] += br[e];

    float lmax = acc[0]; int emax = 0;
#pragma unroll
    for (int e = 1; e < NE; ++e) if (acc[e] > lmax) { lmax = acc[e]; emax = e; }
    float S = 0.f;
#pragma unroll
    for (int e = 0; e < NE; ++e) S += expf(acc[e] - lmax);

    if (S < 2.0f && lane == 0) {   // gate_max = 1/S > 0.5
        int pos = atomicAdd(&counts[emax * CSTRIDE], 1);
        buckets[emax * NTOK + pos] = tok;
    }
}

__device__ __forceinline__ void gload_lds16(const void* g, void* l) {
    __builtin_amdgcn_global_load_lds((const AS1 unsigned int*)g,
                                     (AS3 unsigned int*)l, 16, 0, 0);
}

// ---------- fast path: bf16 grouped GEMM, compacted grid + XOR swizzle ----------
__global__ __launch_bounds__(256) void moe_gemm_bf16_k(
    const ushort_t* __restrict__ xbf, const ushort_t* __restrict__ webf,
    const float* __restrict__ be, float* __restrict__ out,
    const int* __restrict__ counts, const int* __restrict__ buckets)
{
    int cw[NE];
#pragma unroll
    for (int i = 0; i < NE; ++i) cw[i] = counts[i * CSTRIDE];
    const int t = blockIdx.x;
    int base = 0, e = -1, m0 = 0;
#pragma unroll
    for (int i = 0; i < NE; ++i) {
        const int te = (cw[i] + 127) >> 7;
        if (e < 0 && t < base + te) { e = i; m0 = (t - base) << 7; }
        base += te;
    }
    if (e < 0) return;
    const int cnt = cw[e];
    const int n0  = blockIdx.y * 128;

    __shared__ ushort_t As[128 * 64];   // 16 KB, linear (gload_lds dest)
    __shared__ ushort_t Bs[128 * 64];   // 16 KB

    const int tid   = threadIdx.x;
    const int wave  = tid >> 6, lane = tid & 63;
    const int chunk = tid & 7;          // 16B chunk within a 64-elem K-slice
    const int rbase = tid >> 3;         // 0..31

    const ushort_t* asrc[4];
    const ushort_t* bsrc[4];
#pragma unroll
    for (int i = 0; i < 4; ++i) {
        const int row = i * 32 + rbase;            // 0..127
        const int sc  = chunk ^ (row & 7);         // pre-swizzled source chunk
        int mi = m0 + row; if (mi >= cnt) mi = cnt - 1;
        const int tok = buckets[e * NTOK + mi];
        asrc[i] = xbf + (size_t)tok * NC + sc * 8;
        bsrc[i] = webf + ((size_t)(e * 1024 + n0 + row)) * NC + sc * 8;
    }

    const int wm = (wave >> 1) * 64, wn = (wave & 1) * 64;
    const int fr = lane & 15, hi = lane >> 4;

    floatx4 acc[4][4];
#pragma unroll
    for (int m = 0; m < 4; ++m)
#pragma unroll
        for (int n = 0; n < 4; ++n) acc[m][n] = (floatx4)(0.0f);

    for (int k0 = 0; k0 < NC; k0 += 64) {
#pragma unroll
        for (int i = 0; i < 4; ++i)
            gload_lds16(asrc[i] + k0, &As[(i * 256 + tid) * 8]);
#pragma unroll
        for (int i = 0; i < 4; ++i)
            gload_lds16(bsrc[i] + k0, &Bs[(i * 256 + tid) * 8]);
        __syncthreads();   // staging complete
#pragma unroll
        for (int ks = 0; ks < 2; ++ks) {
            bf16x8 af[4], bfv[4];
#pragma unroll
            for (int m = 0; m < 4; ++m) {
                const int row = wm + m * 16 + fr;
                const int cg  = (ks * 4 + hi) ^ (row & 7);   // swizzled read chunk
                af[m] = *(const bf16x8*)((const char*)As + row * 128 + cg * 16);
            }
#pragma unroll
            for (int n = 0; n < 4; ++n) {
                const int row = wn + n * 16 + fr;
                const int cg  = (ks * 4 + hi) ^ (row & 7);
                bfv[n] = *(const bf16x8*)((const char*)Bs + row * 128 + cg * 16);
            }
#pragma unroll
            for (int m = 0; m < 4; ++m)
#pragma unroll
                for (int n = 0; n < 4; ++n)
                    acc[m][n] = __builtin_amdgcn_mfma_f32_16x16x32_bf16(
                        af[m], bfv[n], acc[m][n], 0, 0, 0);
        }
        __syncthreads();   // safe to overwrite LDS
    }

    // Epilogue: D layout col=lane&15, row=(lane>>4)*4+reg (m89-verified)
    const int r4 = (lane >> 4) * 4;
    float bev[4];
#pragma unroll
    for (int n = 0; n < 4; ++n) bev[n] = be[e * NC + n0 + wn + n * 16 + fr];
#pragma unroll
    for (int m = 0; m < 4; ++m) {
#pragma unroll
        for (int j = 0; j < 4; ++j) {
            const int trow = m0 + wm + m * 16 + r4 + j;
            if (trow < cnt) {
                const int tok = buckets[e * NTOK + trow];
                float* orow = out + (size_t)tok * NC + n0 + wn + fr;
#pragma unroll
                for (int n = 0; n < 4; ++n) orow[n * 16] = acc[m][n][j] + bev[n];
            }
        }
    }
}

// ---------- fallback path (fp32 staging, small ws) ----------
#define BM 64
#define BN 64
#define BK 32
#define LPAD 40
__global__ __launch_bounds__(256) void moe_gemm_k(
    const float* __restrict__ x, const float* __restrict__ We,
    const float* __restrict__ be, float* __restrict__ out,
    const int* __restrict__ counts, const int* __restrict__ buckets)
{
    const int e   = blockIdx.z;
    const int cnt = counts[e * CSTRIDE];
    const int m0  = blockIdx.x * BM;
    if (m0 >= cnt) return;
    const int n0  = blockIdx.y * BN;

    __shared__ ushort_t As[BM * LPAD];
    __shared__ ushort_t Bs[BM * LPAD];

    const int tid  = threadIdx.x;
    const int srow = tid >> 2;
    const int scg  = (tid & 3) * 8;

    const int mrow = m0 + srow;
    const int tokA = (mrow < cnt) ? buckets[e * NTOK + mrow] : -1;
    const float* xrow = x + (size_t)(tokA < 0 ? 0 : tokA) * NC;
    const float* wrow = We + ((size_t)e * NC + (n0 + srow)) * NC;

    const int wave = tid >> 6, lane = tid & 63;
    const int wm = (wave >> 1) * 32, wn = (wave & 1) * 32;
    const int fr = lane & 15;
    const int fk = (lane >> 4) * 8;

    floatx4 acc[2][2];
#pragma unroll
    for (int m = 0; m < 2; ++m)
#pragma unroll
        for (int n = 0; n < 2; ++n) acc[m][n] = (floatx4)(0.0f);

    for (int k0 = 0; k0 < NC; k0 += BK) {
        float4 a0 = make_float4(0.f,0.f,0.f,0.f), a1 = a0;
        if (tokA >= 0) {
            a0 = *(const float4*)(xrow + k0 + scg);
            a1 = *(const float4*)(xrow + k0 + scg + 4);
        }
        float4 b0 = *(const float4*)(wrow + k0 + scg);
        float4 b1 = *(const float4*)(wrow + k0 + scg + 4);

        __syncthreads();
        union { bf16x8 v; ushort_t s[8]; } pa, pb;
        pa.s[0] = f2bf(a0.x); pa.s[1] = f2bf(a0.y); pa.s[2] = f2bf(a0.z); pa.s[3] = f2bf(a0.w);
        pa.s[4] = f2bf(a1.x); pa.s[5] = f2bf(a1.y); pa.s[6] = f2bf(a1.z); pa.s[7] = f2bf(a1.w);
        pb.s[0] = f2bf(b0.x); pb.s[1] = f2bf(b0.y); pb.s[2] = f2bf(b0.z); pb.s[3] = f2bf(b0.w);
        pb.s[4] = f2bf(b1.x); pb.s[5] = f2bf(b1.y); pb.s[6] = f2bf(b1.z); pb.s[7] = f2bf(b1.w);
        *(bf16x8*)&As[srow * LPAD + scg] = pa.v;
        *(bf16x8*)&Bs[srow * LPAD + scg] = pb.v;
        __syncthreads();

        bf16x8 af[2], bfr[2];
#pragma unroll
        for (int m = 0; m < 2; ++m)
            af[m] = *(const bf16x8*)&As[(wm + m * 16 + fr) * LPAD + fk];
#pragma unroll
        for (int n = 0; n < 2; ++n)
            bfr[n] = *(const bf16x8*)&Bs[(wn + n * 16 + fr) * LPAD + fk];
#pragma unroll
        for (int m = 0; m < 2; ++m)
#pragma unroll
            for (int n = 0; n < 2; ++n)
                acc[m][n] = __builtin_amdgcn_mfma_f32_16x16x32_bf16(af[m], bfr[n], acc[m][n], 0, 0, 0);
    }

    const int r4 = (lane >> 4) * 4;
#pragma unroll
    for (int m = 0; m < 2; ++m) {
        const int trowb = m0 + wm + m * 16 + r4;
#pragma unroll
        for (int j = 0; j < 4; ++j) {
            const int trow = trowb + j;
            if (trow < cnt) {
                const int tok = buckets[e * NTOK + trow];
#pragma unroll
                for (int n = 0; n < 2; ++n) {
                    const int d = n0 + wn + n * 16 + fr;
                    out[(size_t)tok * NC + d] = acc[m][n][j] + be[e * NC + d];
                }
            }
        }
    }
}

extern "C" void kernel_launch(void* const* d_in, const int* in_sizes, int n_in,
                              void* d_out, int out_size, void* d_ws, size_t ws_size,
                              hipStream_t stream)
{
    const float* x  = (const float*)d_in[0];
    const float* Wr = (const float*)d_in[1];
    const float* br = (const float*)d_in[2];
    const float* We = (const float*)d_in[3];
    const float* be = (const float*)d_in[4];
    float* out = (float*)d_out;

    // ws layout (bytes):
    //   [0, 1024)              padded counts (8 x 128B)
    //   [1024, 1024+262144)    buckets (8 x 8192 ints)      -> ends 263168
    //   [263168, +16777216)    x bf16                        -> ends 17040384
    //   [17040384, +16777216)  We bf16                       -> ends 33817600
    int* counts  = (int*)d_ws;
    int* buckets = (int*)((char*)d_ws + 1024);
    const size_t XBF_OFF = 263168;
    const size_t WBF_OFF = 17040384;
    const size_t WS_NEED = 33817600;
    const bool fast = (ws_size >= WS_NEED);

    ushort_t* xbf  = fast ? (ushort_t*)((char*)d_ws + XBF_OFF) : nullptr;
    ushort_t* webf = fast ? (ushort_t*)((char*)d_ws + WBF_OFF) : nullptr;

    // Graph-capturable memset nodes: counts=0, out=0 (replaces router's
    // divergent zero-row writes; GEMM overwrites routed rows afterwards).
    hipMemsetAsync(d_ws, 0, 1024, stream);
    hipMemsetAsync(d_out, 0, (size_t)out_size * sizeof(float), stream);

    hipLaunchKernelGGL(router_k, dim3(NTOK / 4), dim3(256), 0, stream,
                       x, Wr, br, counts, buckets, xbf, We, webf);
    if (fast) {
        hipLaunchKernelGGL(moe_gemm_bf16_k, dim3(MAXT, NC / 128, 1), dim3(256),
                           0, stream, xbf, webf, be, out, counts, buckets);
    } else {
        hipLaunchKernelGGL(moe_gemm_k, dim3(NTOK / BM, NC / BN, NE), dim3(256),
                           0, stream, x, We, be, out, counts, buckets);
    }
}

// Round 6
// 57.677 us; speedup vs baseline: 2.9900x; 1.1459x over previous
//
#include <hip/hip_runtime.h>
#include <hip/hip_bf16.h>
#include <stdint.h>

// Problem constants (B,T,C,E) = (4,2048,1024,8)
#define NB 4
#define NT 2048
#define NC 1024
#define NE 8
#define NTOK (NB * NT)              // 8192 tokens
#define MAXT (NTOK / 128 + NE - 1)  // 71 worst-case M-tiles across experts
#define CSTRIDE 32                  // counter padding: 32 ints = 128 B / expert

typedef __attribute__((ext_vector_type(4))) float floatx4;
typedef __attribute__((ext_vector_type(8))) __bf16 bf16x8;
typedef __attribute__((ext_vector_type(4))) __bf16 bf16x4;
typedef unsigned short ushort_t;

#define AS1 __attribute__((address_space(1)))
#define AS3 __attribute__((address_space(3)))

__device__ __forceinline__ ushort_t f2bf(float f) {
    uint32_t u = __builtin_bit_cast(uint32_t, f);
    u += 0x7FFFu + ((u >> 16) & 1u);   // round-to-nearest-even
    return (ushort_t)(u >> 16);
}

// One wave per token. Stream-through phases: (A) We->bf16 convert slice with
// immediate stores, (B) x row load, (C) fp32 routing math, (D) routed ->
// {bf16 x row store + bucket atomic} / unrouted -> {zero output row}.
// NO d_out memset in the graph: a captured hipMemsetAsync runs on SDMA at
// ~0.8 TB/s (40 us for 33 MB, measured round 5) — zeroing here is ~3 us.
__global__ __launch_bounds__(256, 4) void router_k(
    const float* __restrict__ x, const float* __restrict__ Wr,
    const float* __restrict__ br, float* __restrict__ out,
    int* __restrict__ counts, int* __restrict__ buckets,
    ushort_t* __restrict__ xbf /* null on fallback */,
    const float* __restrict__ We, ushort_t* __restrict__ webf /* null on fallback */)
{
    const int wave = threadIdx.x >> 6;
    const int lane = threadIdx.x & 63;
    const int tok  = blockIdx.x * 4 + wave;

    // --- Phase A: fused We convert, stream-through (2 x 32B/thread) ---
    if (webf) {
        const size_t cbase = ((size_t)(blockIdx.x * 256 + threadIdx.x)) * 8;
        {
            float4 a = *(const float4*)(We + cbase);
            float4 b = *(const float4*)(We + cbase + 4);
            union { bf16x8 v; ushort_t s[8]; } p;
            p.s[0] = f2bf(a.x); p.s[1] = f2bf(a.y); p.s[2] = f2bf(a.z); p.s[3] = f2bf(a.w);
            p.s[4] = f2bf(b.x); p.s[5] = f2bf(b.y); p.s[6] = f2bf(b.z); p.s[7] = f2bf(b.w);
            *(bf16x8*)(webf + cbase) = p.v;
        }
        {
            float4 a = *(const float4*)(We + cbase + 4194304);
            float4 b = *(const float4*)(We + cbase + 4194304 + 4);
            union { bf16x8 v; ushort_t s[8]; } p;
            p.s[0] = f2bf(a.x); p.s[1] = f2bf(a.y); p.s[2] = f2bf(a.z); p.s[3] = f2bf(a.w);
            p.s[4] = f2bf(b.x); p.s[5] = f2bf(b.y); p.s[6] = f2bf(b.z); p.s[7] = f2bf(b.w);
            *(bf16x8*)(webf + cbase + 4194304) = p.v;
        }
    }

    // --- Phase B: x row load ---
    const float4* xr = (const float4*)(x + (size_t)tok * NC);
    float4 xv[4];
#pragma unroll
    for (int j = 0; j < 4; ++j) xv[j] = xr[lane + 64 * j];

    // --- Phase C: fp32 routing ---
    float acc[NE];
#pragma unroll
    for (int e = 0; e < NE; ++e) {
        const float4* wr = (const float4*)(Wr + e * NC);
        float a = 0.f;
#pragma unroll
        for (int j = 0; j < 4; ++j) {
            float4 w = wr[lane + 64 * j];
            a += xv[j].x * w.x; a += xv[j].y * w.y;
            a += xv[j].z * w.z; a += xv[j].w * w.w;
        }
        acc[e] = a;
    }
#pragma unroll
    for (int off = 32; off >= 1; off >>= 1)
#pragma unroll
        for (int e = 0; e < NE; ++e) acc[e] += __shfl_xor(acc[e], off);

#pragma unroll
    for (int e = 0; e < NE; ++e) acc[e] += br[e];

    float lmax = acc[0]; int emax = 0;
#pragma unroll
    for (int e = 1; e < NE; ++e) if (acc[e] > lmax) { lmax = acc[e]; emax = e; }
    float S = 0.f;
#pragma unroll
    for (int e = 0; e < NE; ++e) S += expf(acc[e] - lmax);

    // --- Phase D: wave-uniform routed/unrouted paths ---
    const bool routed = (S < 2.0f);   // gate_max = 1/S > 0.5
    if (routed) {
        if (xbf) {  // bf16 x row needed only for routed tokens
            union { bf16x4 v; ushort_t s[4]; } p;
#pragma unroll
            for (int j = 0; j < 4; ++j) {
                p.s[0] = f2bf(xv[j].x); p.s[1] = f2bf(xv[j].y);
                p.s[2] = f2bf(xv[j].z); p.s[3] = f2bf(xv[j].w);
                *(bf16x4*)(xbf + (size_t)tok * NC + (lane + 64 * j) * 4) = p.v;
            }
        }
        if (lane == 0) {
            int pos = atomicAdd(&counts[emax * CSTRIDE], 1);
            buckets[emax * NTOK + pos] = tok;
        }
    } else {
        float4 z = make_float4(0.f, 0.f, 0.f, 0.f);
        float4* orow = (float4*)(out + (size_t)tok * NC);
#pragma unroll
        for (int j = 0; j < 4; ++j) orow[lane + 64 * j] = z;
    }
}

__device__ __forceinline__ void gload_lds16(const void* g, void* l) {
    __builtin_amdgcn_global_load_lds((const AS1 unsigned int*)g,
                                     (AS3 unsigned int*)l, 16, 0, 0);
}

// ---------- fast path: bf16 grouped GEMM, compacted grid + XOR swizzle ----------
__global__ __launch_bounds__(256) void moe_gemm_bf16_k(
    const ushort_t* __restrict__ xbf, const ushort_t* __restrict__ webf,
    const float* __restrict__ be, float* __restrict__ out,
    const int* __restrict__ counts, const int* __restrict__ buckets)
{
    int cw[NE];
#pragma unroll
    for (int i = 0; i < NE; ++i) cw[i] = counts[i * CSTRIDE];
    const int t = blockIdx.x;
    int base = 0, e = -1, m0 = 0;
#pragma unroll
    for (int i = 0; i < NE; ++i) {
        const int te = (cw[i] + 127) >> 7;
        if (e < 0 && t < base + te) { e = i; m0 = (t - base) << 7; }
        base += te;
    }
    if (e < 0) return;
    const int cnt = cw[e];
    const int n0  = blockIdx.y * 128;

    __shared__ ushort_t As[128 * 64];   // 16 KB, linear (gload_lds dest)
    __shared__ ushort_t Bs[128 * 64];   // 16 KB

    const int tid   = threadIdx.x;
    const int wave  = tid >> 6, lane = tid & 63;
    const int chunk = tid & 7;          // 16B chunk within a 64-elem K-slice
    const int rbase = tid >> 3;         // 0..31

    const ushort_t* asrc[4];
    const ushort_t* bsrc[4];
#pragma unroll
    for (int i = 0; i < 4; ++i) {
        const int row = i * 32 + rbase;            // 0..127
        const int sc  = chunk ^ (row & 7);         // pre-swizzled source chunk
        int mi = m0 + row; if (mi >= cnt) mi = cnt - 1;
        const int tok = buckets[e * NTOK + mi];
        asrc[i] = xbf + (size_t)tok * NC + sc * 8;
        bsrc[i] = webf + ((size_t)(e * 1024 + n0 + row)) * NC + sc * 8;
    }

    const int wm = (wave >> 1) * 64, wn = (wave & 1) * 64;
    const int fr = lane & 15, hi = lane >> 4;

    floatx4 acc[4][4];
#pragma unroll
    for (int m = 0; m < 4; ++m)
#pragma unroll
        for (int n = 0; n < 4; ++n) acc[m][n] = (floatx4)(0.0f);

    for (int k0 = 0; k0 < NC; k0 += 64) {
#pragma unroll
        for (int i = 0; i < 4; ++i)
            gload_lds16(asrc[i] + k0, &As[(i * 256 + tid) * 8]);
#pragma unroll
        for (int i = 0; i < 4; ++i)
            gload_lds16(bsrc[i] + k0, &Bs[(i * 256 + tid) * 8]);
        __syncthreads();   // staging complete
#pragma unroll
        for (int ks = 0; ks < 2; ++ks) {
            bf16x8 af[4], bfv[4];
#pragma unroll
            for (int m = 0; m < 4; ++m) {
                const int row = wm + m * 16 + fr;
                const int cg  = (ks * 4 + hi) ^ (row & 7);   // swizzled read chunk
                af[m] = *(const bf16x8*)((const char*)As + row * 128 + cg * 16);
            }
#pragma unroll
            for (int n = 0; n < 4; ++n) {
                const int row = wn + n * 16 + fr;
                const int cg  = (ks * 4 + hi) ^ (row & 7);
                bfv[n] = *(const bf16x8*)((const char*)Bs + row * 128 + cg * 16);
            }
#pragma unroll
            for (int m = 0; m < 4; ++m)
#pragma unroll
                for (int n = 0; n < 4; ++n)
                    acc[m][n] = __builtin_amdgcn_mfma_f32_16x16x32_bf16(
                        af[m], bfv[n], acc[m][n], 0, 0, 0);
        }
        __syncthreads();   // safe to overwrite LDS
    }

    // Epilogue: D layout col=lane&15, row=(lane>>4)*4+reg (m89-verified)
    const int r4 = (lane >> 4) * 4;
    float bev[4];
#pragma unroll
    for (int n = 0; n < 4; ++n) bev[n] = be[e * NC + n0 + wn + n * 16 + fr];
#pragma unroll
    for (int m = 0; m < 4; ++m) {
#pragma unroll
        for (int j = 0; j < 4; ++j) {
            const int trow = m0 + wm + m * 16 + r4 + j;
            if (trow < cnt) {
                const int tok = buckets[e * NTOK + trow];
                float* orow = out + (size_t)tok * NC + n0 + wn + fr;
#pragma unroll
                for (int n = 0; n < 4; ++n) orow[n * 16] = acc[m][n][j] + bev[n];
            }
        }
    }
}

// ---------- fallback path (fp32 staging, small ws) ----------
#define BM 64
#define BN 64
#define BK 32
#define LPAD 40
__global__ __launch_bounds__(256) void moe_gemm_k(
    const float* __restrict__ x, const float* __restrict__ We,
    const float* __restrict__ be, float* __restrict__ out,
    const int* __restrict__ counts, const int* __restrict__ buckets)
{
    const int e   = blockIdx.z;
    const int cnt = counts[e * CSTRIDE];
    const int m0  = blockIdx.x * BM;
    if (m0 >= cnt) return;
    const int n0  = blockIdx.y * BN;

    __shared__ ushort_t As[BM * LPAD];
    __shared__ ushort_t Bs[BM * LPAD];

    const int tid  = threadIdx.x;
    const int srow = tid >> 2;
    const int scg  = (tid & 3) * 8;

    const int mrow = m0 + srow;
    const int tokA = (mrow < cnt) ? buckets[e * NTOK + mrow] : -1;
    const float* xrow = x + (size_t)(tokA < 0 ? 0 : tokA) * NC;
    const float* wrow = We + ((size_t)e * NC + (n0 + srow)) * NC;

    const int wave = tid >> 6, lane = tid & 63;
    const int wm = (wave >> 1) * 32, wn = (wave & 1) * 32;
    const int fr = lane & 15;
    const int fk = (lane >> 4) * 8;

    floatx4 acc[2][2];
#pragma unroll
    for (int m = 0; m < 2; ++m)
#pragma unroll
        for (int n = 0; n < 2; ++n) acc[m][n] = (floatx4)(0.0f);

    for (int k0 = 0; k0 < NC; k0 += BK) {
        float4 a0 = make_float4(0.f,0.f,0.f,0.f), a1 = a0;
        if (tokA >= 0) {
            a0 = *(const float4*)(xrow + k0 + scg);
            a1 = *(const float4*)(xrow + k0 + scg + 4);
        }
        float4 b0 = *(const float4*)(wrow + k0 + scg);
        float4 b1 = *(const float4*)(wrow + k0 + scg + 4);

        __syncthreads();
        union { bf16x8 v; ushort_t s[8]; } pa, pb;
        pa.s[0] = f2bf(a0.x); pa.s[1] = f2bf(a0.y); pa.s[2] = f2bf(a0.z); pa.s[3] = f2bf(a0.w);
        pa.s[4] = f2bf(a1.x); pa.s[5] = f2bf(a1.y); pa.s[6] = f2bf(a1.z); pa.s[7] = f2bf(a1.w);
        pb.s[0] = f2bf(b0.x); pb.s[1] = f2bf(b0.y); pb.s[2] = f2bf(b0.z); pb.s[3] = f2bf(b0.w);
        pb.s[4] = f2bf(b1.x); pb.s[5] = f2bf(b1.y); pb.s[6] = f2bf(b1.z); pb.s[7] = f2bf(b1.w);
        *(bf16x8*)&As[srow * LPAD + scg] = pa.v;
        *(bf16x8*)&Bs[srow * LPAD + scg] = pb.v;
        __syncthreads();

        bf16x8 af[2], bfr[2];
#pragma unroll
        for (int m = 0; m < 2; ++m)
            af[m] = *(const bf16x8*)&As[(wm + m * 16 + fr) * LPAD + fk];
#pragma unroll
        for (int n = 0; n < 2; ++n)
            bfr[n] = *(const bf16x8*)&Bs[(wn + n * 16 + fr) * LPAD + fk];
#pragma unroll
        for (int m = 0; m < 2; ++m)
#pragma unroll
            for (int n = 0; n < 2; ++n)
                acc[m][n] = __builtin_amdgcn_mfma_f32_16x16x32_bf16(af[m], bfr[n], acc[m][n], 0, 0, 0);
    }

    const int r4 = (lane >> 4) * 4;
#pragma unroll
    for (int m = 0; m < 2; ++m) {
        const int trowb = m0 + wm + m * 16 + r4;
#pragma unroll
        for (int j = 0; j < 4; ++j) {
            const int trow = trowb + j;
            if (trow < cnt) {
                const int tok = buckets[e * NTOK + trow];
#pragma unroll
                for (int n = 0; n < 2; ++n) {
                    const int d = n0 + wn + n * 16 + fr;
                    out[(size_t)tok * NC + d] = acc[m][n][j] + be[e * NC + d];
                }
            }
        }
    }
}

extern "C" void kernel_launch(void* const* d_in, const int* in_sizes, int n_in,
                              void* d_out, int out_size, void* d_ws, size_t ws_size,
                              hipStream_t stream)
{
    const float* x  = (const float*)d_in[0];
    const float* Wr = (const float*)d_in[1];
    const float* br = (const float*)d_in[2];
    const float* We = (const float*)d_in[3];
    const float* be = (const float*)d_in[4];
    float* out = (float*)d_out;

    // ws layout (bytes):
    //   [0, 1024)              padded counts (8 x 128B)
    //   [1024, 1024+262144)    buckets (8 x 8192 ints)      -> ends 263168
    //   [263168, +16777216)    x bf16                        -> ends 17040384
    //   [17040384, +16777216)  We bf16                       -> ends 33817600
    int* counts  = (int*)d_ws;
    int* buckets = (int*)((char*)d_ws + 1024);
    const size_t XBF_OFF = 263168;
    const size_t WBF_OFF = 17040384;
    const size_t WS_NEED = 33817600;
    const bool fast = (ws_size >= WS_NEED);

    ushort_t* xbf  = fast ? (ushort_t*)((char*)d_ws + XBF_OFF) : nullptr;
    ushort_t* webf = fast ? (ushort_t*)((char*)d_ws + WBF_OFF) : nullptr;

    // Tiny counts clear only (1 KB on SDMA is negligible; do NOT memset d_out
    // in the graph — SDMA fill runs at ~0.8 TB/s, measured 40 us for 33 MB).
    hipMemsetAsync(d_ws, 0, 1024, stream);

    hipLaunchKernelGGL(router_k, dim3(NTOK / 4), dim3(256), 0, stream,
                       x, Wr, br, out, counts, buckets, xbf, We, webf);
    if (fast) {
        hipLaunchKernelGGL(moe_gemm_bf16_k, dim3(MAXT, NC / 128, 1), dim3(256),
                           0, stream, xbf, webf, be, out, counts, buckets);
    } else {
        hipLaunchKernelGGL(moe_gemm_k, dim3(NTOK / BM, NC / BN, NE), dim3(256),
                           0, stream, x, We, be, out, counts, buckets);
    }
}